// Round 5
// baseline (2032.243 us; speedup 1.0000x reference)
//
#include <hip/hip_runtime.h>

// CANPathIntegrator — R10: R9 + __launch_bounds__(1024, 4).
//
// R9 post-mortem: VGPR_Count=64 + FETCH 3.06GB + WRITE 2.56GB (output is
// only 135MB) = the 64-reg accumulator block spilled to scratch. With
// __launch_bounds__(1024) and no occupancy arg, the compiler targeted
// 8 waves/SIMD and capped VGPRs at 64; every inner-loop iteration then
// streamed acc spills through HBM at 2.7TB/s (the 2ms was scratch-BW-bound).
// Fix: __launch_bounds__(1024, 4) = 4 waves/EU = 1 block/CU (matching the
// LDS pad), raising the cap to 128 VGPRs — peak live ~110-125 fits.
//
// Structure (verified correct in R9, absmax 0.0078):
//  * z_t = R(omega@S_t) z0 (block-diag rotations commute) -> serial part
//    tracks only x_t, S_t; z_seq/x_seq regenerated in a fused epilogue.
//  * 256 blocks = 64 groups x 4 slices; slice = 128 A-rows; per-step each
//    block streams its 256KB A slice from L2 (L2-resident, 13MB FETCH in
//    R7) and contracts partial-w against xi = rot90(zx)*omega IMMEDIATELY
//    (linear in w -> w never materialized, no wpart LDS, no P3 phase).
//  * zxc swizzle rofs(r)=12r+4*((r>>3)&7)+32*(r>>6): injective (R9 fix),
//    broadcast main-loop reads, conflict-spread contract reads.
//  * 17-shfl halving wave reduction (16 vals -> lane 4j holds val j).
//  * Flag-based slice exchange via MALL: store 16 partials, vmcnt drain,
//    bump seq word; 64 lanes poll 4 slices in parallel. part[] is
//    double-buffered by t&1.

namespace {
constexpr int NT  = 128;   // time steps
constexpr int DD  = 512;   // latent dim
constexpr int KP  = 256;   // rotation pairs
constexpr int NS  = 4;     // row slices (128 rows each)
constexpr int NG  = 64;    // batch groups
constexpr int NB  = 8;     // batches per group
constexpr int NBLK = NG * NS;  // 256 = #CUs
constexpr size_t SEQ_BYTES = (size_t)NG * NS * 16 * 4;   // 16 KB

__device__ __forceinline__ int rofs(int r) {   // injective swizzled offset
    return 12 * r + 4 * ((r >> 3) & 7) + 32 * (r >> 6);
}
}

struct __align__(16) Shm {
    float  zxc[6400];          // 25600 B  row r at rofs(r), 8 batches
    float2 dpi[NB][NT];        //  8192 B
    float2 om[KP];             //  2048 B
    float2 v[KP];              //  2048 B  normalized z0_base pairs
    float  wred[16][16];       //  1024 B  per-wave reduced d partials
    float  Sh[NT][NB][2];      //  8192 B  S_t history (epilogue input)
    float  xh[NT][NB][2];      //  8192 B  x_t history
    float2 x[NB];              // current x (redundant per slice, identical)
    float  nred[16];
    float  pad[7168];          // 28672 B -> total 84096 B > 80KB: 1 blk/CU
};

__global__ __launch_bounds__(1024, 4) void can_main(
    const float* __restrict__ dx_pi, const float* __restrict__ z0,
    const float* __restrict__ x0, const float* __restrict__ omega,
    const float* __restrict__ A, const float* __restrict__ z0b,
    float* __restrict__ d_out,
    unsigned* __restrict__ seq, float* __restrict__ part)
{
    __shared__ Shm sh;
    const int tid = threadIdx.x;
    const int g   = blockIdx.x >> 2;    // batch group
    const int s   = blockIdx.x & 3;     // row slice: rows 128s..128s+127
    const int b0  = NB * g;

    float* z_seq = d_out;
    float* x_seq = d_out + (size_t)512 * NT * DD;

    if (dx_pi == nullptr) ((volatile float*)sh.pad)[0] = 1.f;  // keep pad live

    // ---- preloads ----
    {
        int bb = tid >> 7, tt = tid & 127;
        sh.dpi[bb][tt] =
            reinterpret_cast<const float2*>(dx_pi)[(size_t)(b0 + bb) * NT + tt];
    }
    if (tid < KP) sh.om[tid] = reinterpret_cast<const float2*>(omega)[tid];

    // ||z0_base|| -> normalize once (rotation-invariant)
    float sq = 0.f;
    if (tid < DD) { float f = z0b[tid]; sq = f * f; }
    #pragma unroll
    for (int o = 1; o < 64; o <<= 1) sq += __shfl_xor(sq, o, 64);
    if ((tid & 63) == 0) sh.nred[tid >> 6] = sq;
    __syncthreads();
    float nsq = 0.f;
    #pragma unroll
    for (int w = 0; w < 16; ++w) nsq += sh.nred[w];
    const float zinv = 1.0f / (sqrtf(nsq) + 1e-5f);
    if (tid < KP) {
        float2 vv = reinterpret_cast<const float2*>(z0b)[tid];
        sh.v[tid] = make_float2(vv.x * zinv, vv.y * zinv);
    }

    // persistent x / S state: thread v<16 owns (b = v&7, comp = v>>3)
    float xreg = 0.f, Sreg = 0.f;
    if (tid < 16) {
        int b = tid & 7, comp = tid >> 3;
        xreg = x0[(size_t)(b0 + b) * 2 + comp];
        reinterpret_cast<float*>(&sh.x[b])[comp] = xreg;
    }
    __syncthreads();

    // role constants
    const int rq  = tid >> 6;            // row chunk: rows 8rq..8rq+7 of slice
    const int cq  = tid & 63;            // col oct:   cols 8cq..8cq+7
    const int rg0 = 128 * s + 8 * rq;    // first global row
    const float4* Ap = reinterpret_cast<const float4*>(A)
                       + (size_t)rg0 * 128 + 2 * cq;
    const int zb  = rofs(rg0);           // +12 per row (same 8-block)
    const int c0  = 8 * cq;
    const int lane = tid & 63;
    const int s5 = (lane >> 5) & 1, s4 = (lane >> 4) & 1;
    const int s3 = (lane >> 3) & 1, s2 = (lane >> 2) & 1;

    unsigned* seqp = seq + (g * 4 + s) * 16;

    for (int t = 0; t < NT; ++t) {
        // ---- P1: zx row r (8 batches) = T(omega@x) z0hat ----
        {
            int k1 = tid >> 2, bq = tid & 3;
            float2 o2 = sh.om[k1];
            float2 vv = sh.v[k1];
            int ro0 = rofs(2 * k1);      // rofs(2k1+1) = ro0 + 12
            #pragma unroll
            for (int j = 0; j < 2; ++j) {
                int b = 2 * bq + j;
                float2 xb = sh.x[b];
                float th = o2.x * xb.x + o2.y * xb.y;
                float sn, cs;
                __sincosf(th, &sn, &cs);
                sh.zxc[ro0 + b]      = cs * vv.x - sn * vv.y;
                sh.zxc[ro0 + 12 + b] = sn * vv.x + cs * vv.y;
            }
        }
        __syncthreads();

        // ---- P2: 8-row x 8-col x 8-batch matvec partial in registers ----
        float4 accA[8], accB[8];
        #pragma unroll
        for (int c = 0; c < 8; ++c) {
            accA[c] = make_float4(0.f, 0.f, 0.f, 0.f);
            accB[c] = make_float4(0.f, 0.f, 0.f, 0.f);
        }
        #pragma unroll
        for (int jr = 0; jr < 8; ++jr) {
            float4 a0 = Ap[(size_t)jr * 128];
            float4 a1 = Ap[(size_t)jr * 128 + 1];
            float4 zA = *reinterpret_cast<const float4*>(&sh.zxc[zb + 12 * jr]);
            float4 zB = *reinterpret_cast<const float4*>(&sh.zxc[zb + 12 * jr + 4]);
            float aw[8];
            aw[0] = a0.x; aw[1] = a0.y; aw[2] = a0.z; aw[3] = a0.w;
            aw[4] = a1.x; aw[5] = a1.y; aw[6] = a1.z; aw[7] = a1.w;
            #pragma unroll
            for (int c = 0; c < 8; ++c) {
                accA[c].x = fmaf(aw[c], zA.x, accA[c].x);
                accA[c].y = fmaf(aw[c], zA.y, accA[c].y);
                accA[c].z = fmaf(aw[c], zA.z, accA[c].z);
                accA[c].w = fmaf(aw[c], zA.w, accA[c].w);
                accB[c].x = fmaf(aw[c], zB.x, accB[c].x);
                accB[c].y = fmaf(aw[c], zB.y, accB[c].y);
                accB[c].z = fmaf(aw[c], zB.z, accB[c].z);
                accB[c].w = fmaf(aw[c], zB.w, accB[c].w);
            }
        }

        // ---- contract partial-w against xi (valid by linearity):
        //      g_p = w[2p+1]*zx[2p] - w[2p]*zx[2p+1]; d += g_p * om_p ----
        float4 d0A = make_float4(0,0,0,0), d0B = d0A, d1A = d0A, d1B = d0A;
        {
            float2 omp_[4];
            *reinterpret_cast<float4*>(&omp_[0]) =
                *reinterpret_cast<const float4*>(&sh.om[4 * cq]);
            *reinterpret_cast<float4*>(&omp_[2]) =
                *reinterpret_cast<const float4*>(&sh.om[4 * cq + 2]);
            #pragma unroll
            for (int p = 0; p < 4; ++p) {
                int rl = rofs(c0 + 2 * p);   // rofs(c0+2p+1) = rl + 12
                float4 zl0 = *reinterpret_cast<const float4*>(&sh.zxc[rl]);
                float4 zl1 = *reinterpret_cast<const float4*>(&sh.zxc[rl + 4]);
                float4 zh0 = *reinterpret_cast<const float4*>(&sh.zxc[rl + 12]);
                float4 zh1 = *reinterpret_cast<const float4*>(&sh.zxc[rl + 16]);
                float4 wl  = accA[2 * p], wh = accA[2 * p + 1];
                float4 gl  = accB[2 * p], gh = accB[2 * p + 1];
                float4 gA, gB;
                gA.x = fmaf(wh.x, zl0.x, -wl.x * zh0.x);
                gA.y = fmaf(wh.y, zl0.y, -wl.y * zh0.y);
                gA.z = fmaf(wh.z, zl0.z, -wl.z * zh0.z);
                gA.w = fmaf(wh.w, zl0.w, -wl.w * zh0.w);
                gB.x = fmaf(gh.x, zl1.x, -gl.x * zh1.x);
                gB.y = fmaf(gh.y, zl1.y, -gl.y * zh1.y);
                gB.z = fmaf(gh.z, zl1.z, -gl.z * zh1.z);
                gB.w = fmaf(gh.w, zl1.w, -gl.w * zh1.w);
                float ox = omp_[p].x, oy = omp_[p].y;
                d0A.x = fmaf(gA.x, ox, d0A.x); d1A.x = fmaf(gA.x, oy, d1A.x);
                d0A.y = fmaf(gA.y, ox, d0A.y); d1A.y = fmaf(gA.y, oy, d1A.y);
                d0A.z = fmaf(gA.z, ox, d0A.z); d1A.z = fmaf(gA.z, oy, d1A.z);
                d0A.w = fmaf(gA.w, ox, d0A.w); d1A.w = fmaf(gA.w, oy, d1A.w);
                d0B.x = fmaf(gB.x, ox, d0B.x); d1B.x = fmaf(gB.x, oy, d1B.x);
                d0B.y = fmaf(gB.y, ox, d0B.y); d1B.y = fmaf(gB.y, oy, d1B.y);
                d0B.z = fmaf(gB.z, ox, d0B.z); d1B.z = fmaf(gB.z, oy, d1B.z);
                d0B.w = fmaf(gB.w, ox, d0B.w); d1B.w = fmaf(gB.w, oy, d1B.w);
            }
        }

        // ---- halving wave reduction: 16 values over 64 lanes, 17 shfls.
        //      value v = comp*8 + b; after stages lane 4j holds value j ----
        {
            float r_[16];
            *reinterpret_cast<float4*>(&r_[0])  = d0A;
            *reinterpret_cast<float4*>(&r_[4])  = d0B;
            *reinterpret_cast<float4*>(&r_[8])  = d1A;
            *reinterpret_cast<float4*>(&r_[12]) = d1B;
            #pragma unroll
            for (int k = 0; k < 8; ++k) {     // offset 32: split v bit3 by s5
                float snd = s5 ? r_[k] : r_[k + 8];
                float rcv = __shfl_xor(snd, 32, 64);
                r_[k] = (s5 ? r_[k + 8] : r_[k]) + rcv;
            }
            #pragma unroll
            for (int k = 0; k < 4; ++k) {     // offset 16: split by s4
                float snd = s4 ? r_[k] : r_[k + 4];
                float rcv = __shfl_xor(snd, 16, 64);
                r_[k] = (s4 ? r_[k + 4] : r_[k]) + rcv;
            }
            #pragma unroll
            for (int k = 0; k < 2; ++k) {     // offset 8: split by s3
                float snd = s3 ? r_[k] : r_[k + 2];
                float rcv = __shfl_xor(snd, 8, 64);
                r_[k] = (s3 ? r_[k + 2] : r_[k]) + rcv;
            }
            {                                  // offset 4: split by s2
                float snd = s2 ? r_[0] : r_[1];
                float rcv = __shfl_xor(snd, 4, 64);
                r_[0] = (s2 ? r_[1] : r_[0]) + rcv;
            }
            r_[0] += __shfl_xor(r_[0], 2, 64); // fold lane bits 1,0
            r_[0] += __shfl_xor(r_[0], 1, 64);
            if ((lane & 3) == 0)               // lane 4j holds value j
                sh.wred[rq][lane >> 2] = r_[0];
        }
        __syncthreads();

        // ---- publish: fold 16 waves, store partials, drain, bump seq ----
        float* pbuf = part + ((size_t)(t & 1) * NG + g) * (NS * 16);
        if (tid < 16) {
            float ssum = 0.f;
            #pragma unroll
            for (int w = 0; w < 16; ++w) ssum += sh.wred[w][tid];
            __hip_atomic_store(pbuf + s * 16 + tid, ssum,
                               __ATOMIC_RELAXED, __HIP_MEMORY_SCOPE_AGENT);
        }
        asm volatile("s_waitcnt vmcnt(0)" ::: "memory");
        if (tid == 0)
            __hip_atomic_store(seqp, (unsigned)(t + 1),
                               __ATOMIC_RELAXED, __HIP_MEMORY_SCOPE_AGENT);

        // ---- consume: 64 lanes poll 4 slices in parallel, then reduce ----
        float val = 0.f;
        if (tid < 64) {
            int sl = tid >> 4, v = tid & 15;
            unsigned* sq2 = seq + (g * 4 + sl) * 16;
            while (__hip_atomic_load(sq2, __ATOMIC_RELAXED,
                                     __HIP_MEMORY_SCOPE_AGENT)
                   < (unsigned)(t + 1))
                __builtin_amdgcn_s_sleep(1);
            __atomic_signal_fence(__ATOMIC_ACQUIRE);
            val = __hip_atomic_load(pbuf + sl * 16 + v,
                                    __ATOMIC_RELAXED, __HIP_MEMORY_SCOPE_AGENT);
            val += __shfl_xor(val, 16, 64);
            val += __shfl_xor(val, 32, 64);
        }
        if (tid < 16) {
            int b = tid & 7, comp = tid >> 3;
            float pi = reinterpret_cast<const float*>(&sh.dpi[b][t])[comp];
            float dtv = fmaf(0.1f, val, pi);
            Sreg += dtv;                                  // unclipped cumsum
            xreg = fminf(fmaxf(xreg + dtv, 0.f), 2.0f);   // clipped x
            reinterpret_cast<float*>(&sh.x[b])[comp] = xreg;
            sh.Sh[t][b][comp] = Sreg;
            sh.xh[t][b][comp] = xreg;
        }
        __syncthreads();
    }

    // ---- epilogue: z_seq[b][t][slice cols] = R(omega@S_t) z0[b] ----
    {
        int th2 = tid >> 9, b = (tid >> 6) & 7, kk = tid & 63;
        float2 zp = reinterpret_cast<const float2*>(z0)
                        [(size_t)(b0 + b) * KP + 64 * s + kk];
        float2 o2 = sh.om[64 * s + kk];
        float2* zout = reinterpret_cast<float2*>(z_seq)
                       + (size_t)(b0 + b) * NT * KP + (64 * s + kk);
        for (int tt2 = th2 * 64, e = th2 * 64 + 64; tt2 < e; ++tt2) {
            float Sx = sh.Sh[tt2][b][0], Sy = sh.Sh[tt2][b][1];
            float th = o2.x * Sx + o2.y * Sy;
            float sn, cs;
            __sincosf(th, &sn, &cs);
            zout[(size_t)tt2 * KP] =
                make_float2(cs * zp.x - sn * zp.y, sn * zp.x + cs * zp.y);
        }
    }
    if (s == 0) {   // x_seq from LDS history, coalesced
        int b = tid >> 7, tt3 = tid & 127;
        float2 xv = *reinterpret_cast<const float2*>(&sh.xh[tt3][b][0]);
        reinterpret_cast<float2*>(x_seq)[(size_t)(b0 + b) * NT + tt3] = xv;
    }
}

extern "C" void kernel_launch(void* const* d_in, const int* in_sizes, int n_in,
                              void* d_out, int out_size, void* d_ws, size_t ws_size,
                              hipStream_t stream) {
    (void)in_sizes; (void)n_in; (void)out_size; (void)ws_size;
    unsigned* seq = reinterpret_cast<unsigned*>(d_ws);
    float* part = reinterpret_cast<float*>(
        reinterpret_cast<char*>(d_ws) + SEQ_BYTES);
    hipMemsetAsync(d_ws, 0, SEQ_BYTES, stream);   // zero seq words
    hipLaunchKernelGGL(can_main, dim3(NBLK), dim3(1024), 0, stream,
                       (const float*)d_in[0], (const float*)d_in[1],
                       (const float*)d_in[2], (const float*)d_in[3],
                       (const float*)d_in[4], (const float*)d_in[5],
                       (float*)d_out, seq, part);
}

// Round 6
// 935.590 us; speedup vs baseline: 2.1722x; 2.1722x over previous
//
#include <hip/hip_runtime.h>

// CANPathIntegrator — R11: kill the register spill (two independent fixes).
//
// R10 post-mortem: __launch_bounds__(1024,4) changed NOTHING (VGPR 64->64,
// FETCH/WRITE identical) — it only raises the min-waves floor; the
// allocator still targeted 8 waves/SIMD (64-VGPR cap) and spilled ~18
// dwords/thread/step -> 5.7GB scratch traffic = the whole 2.1ms.
// A 1024-thread workgroup with 84KB LDS is hardware-pinned to 4 waves/SIMD
// anyway, so a 128-reg budget costs zero occupancy. Fixes:
//  (1) amdgpu_waves_per_eu(4,4): explicit min AND MAX (launch_bounds can't
//      express the max) -> allocator targets exactly 4 waves/EU -> 128 regs.
//  (2) Structural: split P2+contract into two column-half passes. Per pass:
//      acc = 4 cols x 8 batches = 32 regs; d-accs (16) live only inside the
//      pass (each pass does its own 17-shfl reduce; pass 1 adds into
//      wred[rq][j] — same thread+slot, race-free). Peak live ~55-70, so
//      even a 64-reg budget spills almost nothing. A traffic unchanged
//      (each A float4 read once across the passes); cost = +16 zx broadcast
//      reads + 17 shfls ~ +0.5us/step.
//
// Structure otherwise = R9/R10 (verified, absmax 0.0078): z_t = R(omega@
// S_t) z0 (rotations commute) -> serial part tracks only x,S; fused
// epilogue regenerates z_seq/x_seq; 64 groups x 4 slices; per-step 256KB
// L2-resident A slice per block; w never materialized (xi-contract by
// linearity); injective zxc swizzle; flag-based MALL slice exchange.

namespace {
constexpr int NT  = 128;   // time steps
constexpr int DD  = 512;   // latent dim
constexpr int KP  = 256;   // rotation pairs
constexpr int NS  = 4;     // row slices (128 rows each)
constexpr int NG  = 64;    // batch groups
constexpr int NB  = 8;     // batches per group
constexpr int NBLK = NG * NS;  // 256 = #CUs
constexpr size_t SEQ_BYTES = (size_t)NG * NS * 16 * 4;   // 16 KB

__device__ __forceinline__ int rofs(int r) {   // injective swizzled offset
    return 12 * r + 4 * ((r >> 3) & 7) + 32 * (r >> 6);
}
}

struct __align__(16) Shm {
    float  zxc[6400];          // 25600 B  row r at rofs(r), 8 batches
    float2 dpi[NB][NT];        //  8192 B
    float2 om[KP];             //  2048 B
    float2 v[KP];              //  2048 B  normalized z0_base pairs
    float  wred[16][16];       //  1024 B  per-wave reduced d partials
    float  Sh[NT][NB][2];      //  8192 B  S_t history (epilogue input)
    float  xh[NT][NB][2];      //  8192 B  x_t history
    float2 x[NB];              // current x (redundant per slice, identical)
    float  nred[16];
    float  pad[7168];          // 28672 B -> total 84096 B > 80KB: 1 blk/CU
};

__attribute__((amdgpu_flat_work_group_size(1024, 1024),
               amdgpu_waves_per_eu(4, 4)))
__global__ void can_main(
    const float* __restrict__ dx_pi, const float* __restrict__ z0,
    const float* __restrict__ x0, const float* __restrict__ omega,
    const float* __restrict__ A, const float* __restrict__ z0b,
    float* __restrict__ d_out,
    unsigned* __restrict__ seq, float* __restrict__ part)
{
    __shared__ Shm sh;
    const int tid = threadIdx.x;
    const int g   = blockIdx.x >> 2;    // batch group
    const int s   = blockIdx.x & 3;     // row slice: rows 128s..128s+127
    const int b0  = NB * g;

    float* z_seq = d_out;
    float* x_seq = d_out + (size_t)512 * NT * DD;

    if (dx_pi == nullptr) ((volatile float*)sh.pad)[0] = 1.f;  // keep pad live

    // ---- preloads ----
    {
        int bb = tid >> 7, tt = tid & 127;
        sh.dpi[bb][tt] =
            reinterpret_cast<const float2*>(dx_pi)[(size_t)(b0 + bb) * NT + tt];
    }
    if (tid < KP) sh.om[tid] = reinterpret_cast<const float2*>(omega)[tid];

    // ||z0_base|| -> normalize once (rotation-invariant)
    float sq = 0.f;
    if (tid < DD) { float f = z0b[tid]; sq = f * f; }
    #pragma unroll
    for (int o = 1; o < 64; o <<= 1) sq += __shfl_xor(sq, o, 64);
    if ((tid & 63) == 0) sh.nred[tid >> 6] = sq;
    __syncthreads();
    float nsq = 0.f;
    #pragma unroll
    for (int w = 0; w < 16; ++w) nsq += sh.nred[w];
    const float zinv = 1.0f / (sqrtf(nsq) + 1e-5f);
    if (tid < KP) {
        float2 vv = reinterpret_cast<const float2*>(z0b)[tid];
        sh.v[tid] = make_float2(vv.x * zinv, vv.y * zinv);
    }

    // persistent x / S state: thread v<16 owns (b = v&7, comp = v>>3)
    float xreg = 0.f, Sreg = 0.f;
    if (tid < 16) {
        int b = tid & 7, comp = tid >> 3;
        xreg = x0[(size_t)(b0 + b) * 2 + comp];
        reinterpret_cast<float*>(&sh.x[b])[comp] = xreg;
    }
    __syncthreads();

    // role constants
    const int rq  = tid >> 6;            // row chunk: rows 8rq..8rq+7 of slice
    const int cq  = tid & 63;            // col oct:   cols 8cq..8cq+7
    const int rg0 = 128 * s + 8 * rq;    // first global row
    const float4* Ap = reinterpret_cast<const float4*>(A)
                       + (size_t)rg0 * 128 + 2 * cq;
    const int zb  = rofs(rg0);           // +12 per row (same 8-block)
    const int c0  = 8 * cq;
    const int lane = tid & 63;
    const int s5 = (lane >> 5) & 1, s4 = (lane >> 4) & 1;
    const int s3 = (lane >> 3) & 1, s2 = (lane >> 2) & 1;

    unsigned* seqp = seq + (g * 4 + s) * 16;

    for (int t = 0; t < NT; ++t) {
        // ---- P1: zx row r (8 batches) = T(omega@x) z0hat ----
        {
            int k1 = tid >> 2, bq = tid & 3;
            float2 o2 = sh.om[k1];
            float2 vv = sh.v[k1];
            int ro0 = rofs(2 * k1);      // rofs(2k1+1) = ro0 + 12
            #pragma unroll
            for (int j = 0; j < 2; ++j) {
                int b = 2 * bq + j;
                float2 xb = sh.x[b];
                float th = o2.x * xb.x + o2.y * xb.y;
                float sn, cs;
                __sincosf(th, &sn, &cs);
                sh.zxc[ro0 + b]      = cs * vv.x - sn * vv.y;
                sh.zxc[ro0 + 12 + b] = sn * vv.x + cs * vv.y;
            }
        }
        __syncthreads();

        // ---- P2 + contract in two column-half passes (h = 0,1):
        //      pass h covers thread cols 4h..4h+3 (global c0+4h+..),
        //      pairs p = 2h+pp. acc 32 regs/pass; d-accs local to pass. ----
        #pragma unroll
        for (int h = 0; h < 2; ++h) {
            // matvec partial: 8 rows x 4 cols x 8 batches
            float4 accA[4], accB[4];
            #pragma unroll
            for (int c = 0; c < 4; ++c) {
                accA[c] = make_float4(0.f, 0.f, 0.f, 0.f);
                accB[c] = make_float4(0.f, 0.f, 0.f, 0.f);
            }
            #pragma unroll
            for (int jr = 0; jr < 8; ++jr) {
                float4 a = Ap[(size_t)jr * 128 + h];
                float4 zA = *reinterpret_cast<const float4*>(
                                &sh.zxc[zb + 12 * jr]);
                float4 zB = *reinterpret_cast<const float4*>(
                                &sh.zxc[zb + 12 * jr + 4]);
                float aw[4];
                aw[0] = a.x; aw[1] = a.y; aw[2] = a.z; aw[3] = a.w;
                #pragma unroll
                for (int c = 0; c < 4; ++c) {
                    accA[c].x = fmaf(aw[c], zA.x, accA[c].x);
                    accA[c].y = fmaf(aw[c], zA.y, accA[c].y);
                    accA[c].z = fmaf(aw[c], zA.z, accA[c].z);
                    accA[c].w = fmaf(aw[c], zA.w, accA[c].w);
                    accB[c].x = fmaf(aw[c], zB.x, accB[c].x);
                    accB[c].y = fmaf(aw[c], zB.y, accB[c].y);
                    accB[c].z = fmaf(aw[c], zB.z, accB[c].z);
                    accB[c].w = fmaf(aw[c], zB.w, accB[c].w);
                }
            }

            // contract this half's partial-w against xi (linear in w):
            // g = w[2p+1]*zx[2p] - w[2p]*zx[2p+1]; d += g * om_p
            float4 d0A = make_float4(0,0,0,0), d0B = d0A;
            float4 d1A = d0A, d1B = d0A;
            float4 omv = *reinterpret_cast<const float4*>(
                             &sh.om[4 * cq + 2 * h]);   // pairs 2h, 2h+1
            #pragma unroll
            for (int pp = 0; pp < 2; ++pp) {
                int rl = rofs(c0 + 4 * h + 2 * pp);  // even row; odd = +12
                float4 zl0 = *reinterpret_cast<const float4*>(&sh.zxc[rl]);
                float4 zl1 = *reinterpret_cast<const float4*>(&sh.zxc[rl + 4]);
                float4 zh0 = *reinterpret_cast<const float4*>(&sh.zxc[rl + 12]);
                float4 zh1 = *reinterpret_cast<const float4*>(&sh.zxc[rl + 16]);
                float4 wl = accA[2 * pp], wh = accA[2 * pp + 1];
                float4 gl = accB[2 * pp], gh = accB[2 * pp + 1];
                float4 gA, gB;
                gA.x = fmaf(wh.x, zl0.x, -wl.x * zh0.x);
                gA.y = fmaf(wh.y, zl0.y, -wl.y * zh0.y);
                gA.z = fmaf(wh.z, zl0.z, -wl.z * zh0.z);
                gA.w = fmaf(wh.w, zl0.w, -wl.w * zh0.w);
                gB.x = fmaf(gh.x, zl1.x, -gl.x * zh1.x);
                gB.y = fmaf(gh.y, zl1.y, -gl.y * zh1.y);
                gB.z = fmaf(gh.z, zl1.z, -gl.z * zh1.z);
                gB.w = fmaf(gh.w, zl1.w, -gl.w * zh1.w);
                float ox = pp ? omv.z : omv.x;
                float oy = pp ? omv.w : omv.y;
                d0A.x = fmaf(gA.x, ox, d0A.x); d1A.x = fmaf(gA.x, oy, d1A.x);
                d0A.y = fmaf(gA.y, ox, d0A.y); d1A.y = fmaf(gA.y, oy, d1A.y);
                d0A.z = fmaf(gA.z, ox, d0A.z); d1A.z = fmaf(gA.z, oy, d1A.z);
                d0A.w = fmaf(gA.w, ox, d0A.w); d1A.w = fmaf(gA.w, oy, d1A.w);
                d0B.x = fmaf(gB.x, ox, d0B.x); d1B.x = fmaf(gB.x, oy, d1B.x);
                d0B.y = fmaf(gB.y, ox, d0B.y); d1B.y = fmaf(gB.y, oy, d1B.y);
                d0B.z = fmaf(gB.z, ox, d0B.z); d1B.z = fmaf(gB.z, oy, d1B.z);
                d0B.w = fmaf(gB.w, ox, d0B.w); d1B.w = fmaf(gB.w, oy, d1B.w);
            }

            // halving wave reduction (17 shfls): value v = comp*8 + b;
            // after stages lane 4j holds value j. Pass 1 adds into wred.
            {
                float r_[16];
                *reinterpret_cast<float4*>(&r_[0])  = d0A;
                *reinterpret_cast<float4*>(&r_[4])  = d0B;
                *reinterpret_cast<float4*>(&r_[8])  = d1A;
                *reinterpret_cast<float4*>(&r_[12]) = d1B;
                #pragma unroll
                for (int k = 0; k < 8; ++k) {     // offset 32: v bit3 by s5
                    float snd = s5 ? r_[k] : r_[k + 8];
                    float rcv = __shfl_xor(snd, 32, 64);
                    r_[k] = (s5 ? r_[k + 8] : r_[k]) + rcv;
                }
                #pragma unroll
                for (int k = 0; k < 4; ++k) {     // offset 16: by s4
                    float snd = s4 ? r_[k] : r_[k + 4];
                    float rcv = __shfl_xor(snd, 16, 64);
                    r_[k] = (s4 ? r_[k + 4] : r_[k]) + rcv;
                }
                #pragma unroll
                for (int k = 0; k < 2; ++k) {     // offset 8: by s3
                    float snd = s3 ? r_[k] : r_[k + 2];
                    float rcv = __shfl_xor(snd, 8, 64);
                    r_[k] = (s3 ? r_[k + 2] : r_[k]) + rcv;
                }
                {                                  // offset 4: by s2
                    float snd = s2 ? r_[0] : r_[1];
                    float rcv = __shfl_xor(snd, 4, 64);
                    r_[0] = (s2 ? r_[1] : r_[0]) + rcv;
                }
                r_[0] += __shfl_xor(r_[0], 2, 64);
                r_[0] += __shfl_xor(r_[0], 1, 64);
                if ((lane & 3) == 0) {             // lane 4j owns value j
                    if (h == 0) sh.wred[rq][lane >> 2] = r_[0];
                    else        sh.wred[rq][lane >> 2] += r_[0];
                }
            }
        }
        __syncthreads();

        // ---- publish: fold 16 waves, store partials, drain, bump seq ----
        float* pbuf = part + ((size_t)(t & 1) * NG + g) * (NS * 16);
        if (tid < 16) {
            float ssum = 0.f;
            #pragma unroll
            for (int w = 0; w < 16; ++w) ssum += sh.wred[w][tid];
            __hip_atomic_store(pbuf + s * 16 + tid, ssum,
                               __ATOMIC_RELAXED, __HIP_MEMORY_SCOPE_AGENT);
        }
        asm volatile("s_waitcnt vmcnt(0)" ::: "memory");
        if (tid == 0)
            __hip_atomic_store(seqp, (unsigned)(t + 1),
                               __ATOMIC_RELAXED, __HIP_MEMORY_SCOPE_AGENT);

        // ---- consume: 64 lanes poll 4 slices in parallel, then reduce ----
        float val = 0.f;
        if (tid < 64) {
            int sl = tid >> 4, v = tid & 15;
            unsigned* sq2 = seq + (g * 4 + sl) * 16;
            while (__hip_atomic_load(sq2, __ATOMIC_RELAXED,
                                     __HIP_MEMORY_SCOPE_AGENT)
                   < (unsigned)(t + 1))
                __builtin_amdgcn_s_sleep(1);
            __atomic_signal_fence(__ATOMIC_ACQUIRE);
            val = __hip_atomic_load(pbuf + sl * 16 + v,
                                    __ATOMIC_RELAXED, __HIP_MEMORY_SCOPE_AGENT);
            val += __shfl_xor(val, 16, 64);
            val += __shfl_xor(val, 32, 64);
        }
        if (tid < 16) {
            int b = tid & 7, comp = tid >> 3;
            float pi = reinterpret_cast<const float*>(&sh.dpi[b][t])[comp];
            float dtv = fmaf(0.1f, val, pi);
            Sreg += dtv;                                  // unclipped cumsum
            xreg = fminf(fmaxf(xreg + dtv, 0.f), 2.0f);   // clipped x
            reinterpret_cast<float*>(&sh.x[b])[comp] = xreg;
            sh.Sh[t][b][comp] = Sreg;
            sh.xh[t][b][comp] = xreg;
        }
        __syncthreads();
    }

    // ---- epilogue: z_seq[b][t][slice cols] = R(omega@S_t) z0[b] ----
    {
        int th2 = tid >> 9, b = (tid >> 6) & 7, kk = tid & 63;
        float2 zp = reinterpret_cast<const float2*>(z0)
                        [(size_t)(b0 + b) * KP + 64 * s + kk];
        float2 o2 = sh.om[64 * s + kk];
        float2* zout = reinterpret_cast<float2*>(z_seq)
                       + (size_t)(b0 + b) * NT * KP + (64 * s + kk);
        for (int tt2 = th2 * 64, e = th2 * 64 + 64; tt2 < e; ++tt2) {
            float Sx = sh.Sh[tt2][b][0], Sy = sh.Sh[tt2][b][1];
            float th = o2.x * Sx + o2.y * Sy;
            float sn, cs;
            __sincosf(th, &sn, &cs);
            zout[(size_t)tt2 * KP] =
                make_float2(cs * zp.x - sn * zp.y, sn * zp.x + cs * zp.y);
        }
    }
    if (s == 0) {   // x_seq from LDS history, coalesced
        int b = tid >> 7, tt3 = tid & 127;
        float2 xv = *reinterpret_cast<const float2*>(&sh.xh[tt3][b][0]);
        reinterpret_cast<float2*>(x_seq)[(size_t)(b0 + b) * NT + tt3] = xv;
    }
}

extern "C" void kernel_launch(void* const* d_in, const int* in_sizes, int n_in,
                              void* d_out, int out_size, void* d_ws, size_t ws_size,
                              hipStream_t stream) {
    (void)in_sizes; (void)n_in; (void)out_size; (void)ws_size;
    unsigned* seq = reinterpret_cast<unsigned*>(d_ws);
    float* part = reinterpret_cast<float*>(
        reinterpret_cast<char*>(d_ws) + SEQ_BYTES);
    hipMemsetAsync(d_ws, 0, SEQ_BYTES, stream);   // zero seq words
    hipLaunchKernelGGL(can_main, dim3(NBLK), dim3(1024), 0, stream,
                       (const float*)d_in[0], (const float*)d_in[1],
                       (const float*)d_in[2], (const float*)d_in[3],
                       (const float*)d_in[4], (const float*)d_in[5],
                       (float*)d_out, seq, part);
}